// Round 5
// baseline (9065.105 us; speedup 1.0000x reference)
//
#include <hip/hip_runtime.h>

#define HID 2048
#define NHEADS 32
#define NKV 8
#define HEADD 64
#define BATCH 2
#define SEQ 2048
#define MTOT (BATCH*SEQ)      // 4096
#define KVDIM (NKV*HEADD)     // 512
#define KB64 (HID/32)         // 64 k-blocks

typedef _Float16 hf;
typedef hf hf8 __attribute__((ext_vector_type(8)));
typedef hf hf4 __attribute__((ext_vector_type(4)));
typedef float f32x4 __attribute__((ext_vector_type(4)));

#define MFMA16(a,b,c) __builtin_amdgcn_mfma_f32_16x16x32_f16(a, b, c, 0, 0, 0)

// Panel layout (halves): addr(m,k) = ((m>>4)*(K/32) + (k>>5))*512 + (m&15)*32 + (k&31)
// K = 2048 always -> (m>>4)*64*512 = (m>>4)*32768.

// ---------------------------------------------------------------------------
// split fp32 -> hi/lo fp16 (x256) in panel layout. K fixed = 2048.
// ---------------------------------------------------------------------------
__global__ void split_panel(const float* __restrict__ src, hf* __restrict__ hi,
                            hf* __restrict__ lo, int n)
{
    int idx = (blockIdx.x * blockDim.x + threadIdx.x) * 4;
    if (idx >= n) return;
    const int m = idx >> 11, k = idx & 2047;
    float4 v = *(const float4*)(src + idx);
    float s0 = v.x * 256.f, s1 = v.y * 256.f, s2 = v.z * 256.f, s3 = v.w * 256.f;
    hf h0 = (hf)s0, h1 = (hf)s1, h2 = (hf)s2, h3 = (hf)s3;
    hf4 hv = {h0, h1, h2, h3};
    hf4 lv = {(hf)(s0 - (float)h0), (hf)(s1 - (float)h1),
              (hf)(s2 - (float)h2), (hf)(s3 - (float)h3)};
    const size_t d = (size_t)(m >> 4) * 32768 + (size_t)(k >> 5) * 512
                   + ((m & 15) << 5) + (k & 31);
    *(hf4*)(hi + d) = hv;
    *(hf4*)(lo + d) = lv;
}

// ---------------------------------------------------------------------------
// Streaming GEMM mainloop: LDS-free, fragments direct from panel layout.
// Wave tile 64x64 (4x4 of 16x16), block 128x128, K=2048, split x3.
// ---------------------------------------------------------------------------
#define DECLARE_MAINLOOP \
    f32x4 acc[4][4]; \
    _Pragma("unroll") for (int i = 0; i < 4; ++i) \
    _Pragma("unroll") for (int j = 0; j < 4; ++j) acc[i][j] = {0.f,0.f,0.f,0.f}; \
    const size_t loff = (size_t)(fr * 32 + fq * 8); \
    const size_t a0 = (size_t)((bm + wm) >> 4) * 32768 + loff; \
    const size_t b0 = (size_t)((bn + wn) >> 4) * 32768 + loff; \
    hf8 Fah[2][4], Fal[2][4], Fbh[2][4], Fbl[2][4];

#define LOADSET(s, kb) do { \
    _Pragma("unroll") for (int t = 0; t < 4; ++t) { \
        Fah[s][t] = *(const hf8*)(Ah + a0 + (size_t)t * 32768 + (size_t)(kb) * 512); \
        Fal[s][t] = *(const hf8*)(Al + a0 + (size_t)t * 32768 + (size_t)(kb) * 512); \
        Fbh[s][t] = *(const hf8*)(Bh + b0 + (size_t)t * 32768 + (size_t)(kb) * 512); \
        Fbl[s][t] = *(const hf8*)(Bl + b0 + (size_t)t * 32768 + (size_t)(kb) * 512); \
    } } while (0)

#define MFMASET(s) do { \
    _Pragma("unroll") for (int i = 0; i < 4; ++i) \
    _Pragma("unroll") for (int j = 0; j < 4; ++j) { \
        acc[i][j] = MFMA16(Fah[s][i], Fbh[s][j], acc[i][j]); \
        acc[i][j] = MFMA16(Fah[s][i], Fbl[s][j], acc[i][j]); \
        acc[i][j] = MFMA16(Fal[s][i], Fbh[s][j], acc[i][j]); \
    } } while (0)

#define RUN_MAINLOOP \
    LOADSET(0, 0); \
    for (int kb = 0; kb < KB64; kb += 2) { \
        LOADSET(1, kb + 1); \
        MFMASET(0); \
        if (kb + 2 < KB64) LOADSET(0, kb + 2); \
        MFMASET(1); \
    }

// ---------------------------------------------------------------------------
// Fused Q/K/V projection. grid(24, 32): bx<16 -> Q (hi/lo), 16..19 -> K
// (hi/lo), 20..23 -> V (single fp16, transposed vT[d][MTOT]).
// ---------------------------------------------------------------------------
__global__ __launch_bounds__(256, 2)
void gemm_qkv(const hf* __restrict__ xh, const hf* __restrict__ xl,
              const hf* __restrict__ wqh, const hf* __restrict__ wql,
              const hf* __restrict__ wkh, const hf* __restrict__ wkl,
              const hf* __restrict__ wvh, const hf* __restrict__ wvl,
              hf* __restrict__ qh, hf* __restrict__ ql,
              hf* __restrict__ kh, hf* __restrict__ kl,
              hf* __restrict__ vT)
{
    const int tid = threadIdx.x;
    const int lane = tid & 63, wave = tid >> 6;
    const int fr = lane & 15, fq = lane >> 4;
    const int wm = (wave & 1) * 64, wn = (wave >> 1) * 64;
    const int bm = blockIdx.y * 128;
    const int bx = blockIdx.x;

    const hf *Bh, *Bl;
    hf *Oh = nullptr, *Ol = nullptr;
    int bn, Nout, mode;
    if (bx < 16)      { Bh = wqh; Bl = wql; bn = bx * 128;        Nout = HID;   Oh = qh; Ol = ql; mode = 1; }
    else if (bx < 20) { Bh = wkh; Bl = wkl; bn = (bx - 16) * 128; Nout = KVDIM; Oh = kh; Ol = kl; mode = 1; }
    else              { Bh = wvh; Bl = wvl; bn = (bx - 20) * 128; Nout = KVDIM; mode = 2; }

    const hf* Ah = xh; const hf* Al = xl;
    DECLARE_MAINLOOP
    RUN_MAINLOOP

    if (mode == 1) {
        const float scale = 32.f / 65536.f;
#pragma unroll
        for (int j = 0; j < 4; ++j) {
            const int col = bn + wn + j * 16 + fr;
#pragma unroll
            for (int i = 0; i < 4; ++i) {
                const int row0 = bm + wm + i * 16 + fq * 4;
#pragma unroll
                for (int r = 0; r < 4; ++r) {
                    const size_t idx = (size_t)(row0 + r) * Nout + col;
                    float v = acc[i][j][r] * scale;
                    hf h = (hf)v;
                    Oh[idx] = h;
                    Ol[idx] = (hf)(v - (float)h);
                }
            }
        }
    } else {
        const float scale = 1.f / 65536.f;
#pragma unroll
        for (int j = 0; j < 4; ++j) {
            const int col = bn + wn + j * 16 + fr;             // d index
#pragma unroll
            for (int i = 0; i < 4; ++i) {
                const int row0 = bm + wm + i * 16 + fq * 4;    // seq index
                hf4 pk = {(hf)(acc[i][j][0] * scale), (hf)(acc[i][j][1] * scale),
                          (hf)(acc[i][j][2] * scale), (hf)(acc[i][j][3] * scale)};
                *(hf4*)(vT + (size_t)col * MTOT + row0) = pk;
            }
        }
    }
}

// ---------------------------------------------------------------------------
// Output projection: out = (attn panels) @ Wo^T + bias, fp32 out.
// ---------------------------------------------------------------------------
__global__ __launch_bounds__(256, 2)
void gemm_out(const hf* __restrict__ Ah, const hf* __restrict__ Al,
              const hf* __restrict__ Bh, const hf* __restrict__ Bl,
              const float* __restrict__ bias, float* __restrict__ Cf)
{
    const int tid = threadIdx.x;
    const int lane = tid & 63, wave = tid >> 6;
    const int fr = lane & 15, fq = lane >> 4;
    const int wm = (wave & 1) * 64, wn = (wave >> 1) * 64;
    const int bm = blockIdx.y * 128, bn = blockIdx.x * 128;

    DECLARE_MAINLOOP
    RUN_MAINLOOP

    const float scale = 1.f / 65536.f;
#pragma unroll
    for (int j = 0; j < 4; ++j) {
        const int col = bn + wn + j * 16 + fr;
        const float bv = bias[col];
#pragma unroll
        for (int i = 0; i < 4; ++i) {
            const int row0 = bm + wm + i * 16 + fq * 4;
#pragma unroll
            for (int r = 0; r < 4; ++r)
                Cf[(size_t)(row0 + r) * HID + col] = acc[i][j][r] * scale + bv;
        }
    }
}

// ---------------------------------------------------------------------------
// Attention, S^T orientation (R3 structure + K-prefetch pipeline).
// Block = 256 thr / 4 waves on 4 consecutive q-tiles of ONE head (waves share
// the K/V stream -> L1/L2 hits). Wave-private LDS P tile, NO __syncthreads.
// Next kv-chunk's K hi/lo fragments are prefetched into registers before the
// current chunk's MFMA block to hide L2 latency. launch_bounds(256,2) keeps
// the VGPR cap at 256 (R4 lesson: tighter caps trigger remat -> 1.7GB fetch).
// Output written as split(256*attn) in A-panel layout for gemm_out.
// ---------------------------------------------------------------------------
__global__ __launch_bounds__(256, 2)
void attn_st(const hf* __restrict__ Qhg, const hf* __restrict__ Qlg,
             const hf* __restrict__ Khg, const hf* __restrict__ Klg,
             const hf* __restrict__ Vtg,
             hf* __restrict__ Ohg, hf* __restrict__ Olg)
{
    __shared__ hf Ps[4][64][40];      // [wave][q-row][col chunk=32 + pad]
    const int tid  = threadIdx.x;
    const int lane = tid & 63, wave = tid >> 6;
    const int fr = lane & 15, fq = lane >> 4;
    const int hd = blockIdx.y, b = blockIdx.z;
    const int kvh = hd >> 2;
    const int qbase = blockIdx.x * 256 + wave * 64;
    const float SSCALE = 1.f / 8192.f;

    // persistent Q fragments (B-operand: n=q-row=fr, k=d=fq*8+u+32s)
    hf8 qfh[4][2], qfl[4][2];
#pragma unroll
    for (int nt = 0; nt < 4; ++nt) {
        const size_t rb = (size_t)(b * SEQ + qbase + nt * 16 + fr) * HID + hd * 64;
#pragma unroll
        for (int s = 0; s < 2; ++s) {
            qfh[nt][s] = *(const hf8*)(Qhg + rb + s * 32 + fq * 8);
            qfl[nt][s] = *(const hf8*)(Qlg + rb + s * 32 + fq * 8);
        }
    }

    f32x4 oacc[4][4];                 // O^T tiles [d-tile][q-tile]
#pragma unroll
    for (int i = 0; i < 4; ++i)
#pragma unroll
        for (int j = 0; j < 4; ++j) oacc[i][j] = {0.f, 0.f, 0.f, 0.f};
    float lsum[4] = {0.f, 0.f, 0.f, 0.f};

    const size_t kbase = (size_t)(b * SEQ) * KVDIM + kvh * 64;
    const size_t vbase = (size_t)(kvh * 64) * MTOT + (size_t)(b * SEQ);

    // K fragment double buffer: [buf][mt][s], A-operand rows = kv cols
    hf8 kfh[2][2][2], kfl[2][2][2];

#define LOADK(buf, t0) do { \
    _Pragma("unroll") for (int mt = 0; mt < 2; ++mt) { \
        const size_t kr = kbase + (size_t)((t0) + mt * 16 + fr) * KVDIM; \
        _Pragma("unroll") for (int s = 0; s < 2; ++s) { \
            kfh[buf][mt][s] = *(const hf8*)(Khg + kr + s * 32 + fq * 8); \
            kfl[buf][mt][s] = *(const hf8*)(Klg + kr + s * 32 + fq * 8); \
        } } } while (0)

    LOADK(0, 0);

    for (int it = 0; it < SEQ / 32; ++it) {
        const int t0 = it * 32;
        const int cb = it & 1, nb = cb ^ 1;

        // V fragments for this chunk (issue first; consumed after softmax)
        hf8 vfr[4];
#pragma unroll
        for (int dt = 0; dt < 4; ++dt)
            vfr[dt] = *(const hf8*)(Vtg + vbase + (size_t)(dt * 16 + fr) * MTOT
                                    + t0 + fq * 8);

        // prefetch next chunk's K while this chunk computes
        if (it + 1 < SEQ / 32) LOADK(nb, t0 + 32);

        // S^T = K * Q^T, x3 split
        f32x4 sacc[2][4];
#pragma unroll
        for (int mt = 0; mt < 2; ++mt)
#pragma unroll
            for (int nt = 0; nt < 4; ++nt) sacc[mt][nt] = {0.f, 0.f, 0.f, 0.f};

#pragma unroll
        for (int mt = 0; mt < 2; ++mt)
#pragma unroll
            for (int nt = 0; nt < 4; ++nt)
#pragma unroll
                for (int s = 0; s < 2; ++s) {
                    sacc[mt][nt] = MFMA16(kfh[cb][mt][s], qfh[nt][s], sacc[mt][nt]);
                    sacc[mt][nt] = MFMA16(kfh[cb][mt][s], qfl[nt][s], sacc[mt][nt]);
                    sacc[mt][nt] = MFMA16(kfl[cb][mt][s], qfh[nt][s], sacc[mt][nt]);
                }

        // exp (no max subtraction: |S| <= 6.5), l partials, P -> LDS [q][c]
#pragma unroll
        for (int mt = 0; mt < 2; ++mt)
#pragma unroll
            for (int nt = 0; nt < 4; ++nt) {
                float p0 = __expf(sacc[mt][nt][0] * SSCALE);
                float p1 = __expf(sacc[mt][nt][1] * SSCALE);
                float p2 = __expf(sacc[mt][nt][2] * SSCALE);
                float p3 = __expf(sacc[mt][nt][3] * SSCALE);
                lsum[nt] += (p0 + p1) + (p2 + p3);
                hf4 pk = {(hf)p0, (hf)p1, (hf)p2, (hf)p3};
                *(hf4*)&Ps[wave][nt * 16 + fr][mt * 16 + fq * 4] = pk;
            }

        // O^T += V^T * P^T
        hf8 pa[4];
#pragma unroll
        for (int qt = 0; qt < 4; ++qt)
            pa[qt] = *(const hf8*)&Ps[wave][qt * 16 + fr][fq * 8];
#pragma unroll
        for (int dt = 0; dt < 4; ++dt)
#pragma unroll
            for (int qt = 0; qt < 4; ++qt)
                oacc[dt][qt] = MFMA16(vfr[dt], pa[qt], oacc[dt][qt]);
    }
#undef LOADK

#pragma unroll
    for (int qt = 0; qt < 4; ++qt) {
        lsum[qt] += __shfl_xor(lsum[qt], 16, 64);
        lsum[qt] += __shfl_xor(lsum[qt], 32, 64);
    }

    // epilogue: attn = O/l, store split(256*attn) in A-PANEL layout.
    // lane element: q = qbase+qt*16+fr, k(hidden) = hd*64 + dt*16 + fq*4 + e
#pragma unroll
    for (int qt = 0; qt < 4; ++qt) {
        const float inv = 256.f / lsum[qt];
        const int pq = ((b * SEQ + qbase) >> 4) + qt;
#pragma unroll
        for (int dt = 0; dt < 4; ++dt) {
            float o0 = oacc[dt][qt][0] * inv, o1 = oacc[dt][qt][1] * inv;
            float o2 = oacc[dt][qt][2] * inv, o3 = oacc[dt][qt][3] * inv;
            hf h0 = (hf)o0, h1 = (hf)o1, h2 = (hf)o2, h3 = (hf)o3;
            hf4 hv = {h0, h1, h2, h3};
            hf4 lv = {(hf)(o0 - (float)h0), (hf)(o1 - (float)h1),
                      (hf)(o2 - (float)h2), (hf)(o3 - (float)h3)};
            const int kb = hd * 2 + (dt >> 1);
            const size_t d = (size_t)pq * 32768 + (size_t)kb * 512
                           + fr * 32 + (dt & 1) * 16 + fq * 4;
            *(hf4*)(Ohg + d) = hv;
            *(hf4*)(Olg + d) = lv;
        }
    }
}

// ---------------------------------------------------------------------------
extern "C" void kernel_launch(void* const* d_in, const int* in_sizes, int n_in,
                              void* d_out, int out_size, void* d_ws, size_t ws_size,
                              hipStream_t stream)
{
    const float* x  = (const float*)d_in[0];
    const float* Wq = (const float*)d_in[1];
    const float* Wk = (const float*)d_in[2];
    const float* Wv = (const float*)d_in[3];
    const float* Wo = (const float*)d_in[4];
    const float* bo = (const float*)d_in[5];
    float* out = (float*)d_out;
    (void)in_sizes; (void)n_in; (void)out_size; (void)ws_size;

    // workspace (halves), 116 MB. xh/xl reused as attn-output panels.
    hf* p = (hf*)d_ws;
    hf* xh  = p; p += (size_t)MTOT * HID;
    hf* xl  = p; p += (size_t)MTOT * HID;
    hf* qh  = p; p += (size_t)MTOT * HID;
    hf* ql  = p; p += (size_t)MTOT * HID;
    hf* kh  = p; p += (size_t)MTOT * KVDIM;
    hf* kl  = p; p += (size_t)MTOT * KVDIM;
    hf* vT  = p; p += (size_t)MTOT * KVDIM;
    hf* wqh = p; p += (size_t)HID * HID;
    hf* wql = p; p += (size_t)HID * HID;
    hf* wkh = p; p += (size_t)KVDIM * HID;
    hf* wkl = p; p += (size_t)KVDIM * HID;
    hf* wvh = p; p += (size_t)KVDIM * HID;
    hf* wvl = p; p += (size_t)KVDIM * HID;
    hf* woh = p; p += (size_t)HID * HID;
    hf* wol = p; p += (size_t)HID * HID;

    // prep: split into panel layout (all K = 2048)
    split_panel<<<(MTOT * HID) / 1024, 256, 0, stream>>>(x,  xh,  xl,  MTOT * HID);
    split_panel<<<(HID * HID)  / 1024, 256, 0, stream>>>(Wq, wqh, wql, HID * HID);
    split_panel<<<(KVDIM * HID)/ 1024, 256, 0, stream>>>(Wk, wkh, wkl, KVDIM * HID);
    split_panel<<<(KVDIM * HID)/ 1024, 256, 0, stream>>>(Wv, wvh, wvl, KVDIM * HID);
    split_panel<<<(HID * HID)  / 1024, 256, 0, stream>>>(Wo, woh, wol, HID * HID);

    gemm_qkv<<<dim3(24, MTOT / 128), 256, 0, stream>>>(
        xh, xl, wqh, wql, wkh, wkl, wvh, wvl, qh, ql, kh, kl, vT);

    attn_st<<<dim3(SEQ / 256, NHEADS, BATCH), 256, 0, stream>>>(
        qh, ql, kh, kl, vT, xh, xl);

    gemm_out<<<dim3(HID / 128, MTOT / 128), 256, 0, stream>>>(
        xh, xl, woh, wol, bo, out);
}

// Round 6
// 651.489 us; speedup vs baseline: 13.9144x; 13.9144x over previous
//
#include <hip/hip_runtime.h>

#define HID 2048
#define NHEADS 32
#define NKV 8
#define HEADD 64
#define BATCH 2
#define SEQ 2048
#define MTOT (BATCH*SEQ)      // 4096
#define KVDIM (NKV*HEADD)     // 512
#define KB64 (HID/32)         // 64 k-blocks

typedef _Float16 hf;
typedef hf hf8 __attribute__((ext_vector_type(8)));
typedef hf hf4 __attribute__((ext_vector_type(4)));
typedef float f32x4 __attribute__((ext_vector_type(4)));

#define MFMA16(a,b,c) __builtin_amdgcn_mfma_f32_16x16x32_f16(a, b, c, 0, 0, 0)

// Panel layout (halves): addr(m,k) = ((m>>4)*(K/32) + (k>>5))*512 + (m&15)*32 + (k&31)
// K = 2048 always -> (m>>4)*64*512 = (m>>4)*32768.

// ---------------------------------------------------------------------------
// split fp32 -> hi/lo fp16 (x256) in panel layout. K fixed = 2048.
// ---------------------------------------------------------------------------
__global__ void split_panel(const float* __restrict__ src, hf* __restrict__ hi,
                            hf* __restrict__ lo, int n)
{
    int idx = (blockIdx.x * blockDim.x + threadIdx.x) * 4;
    if (idx >= n) return;
    const int m = idx >> 11, k = idx & 2047;
    float4 v = *(const float4*)(src + idx);
    float s0 = v.x * 256.f, s1 = v.y * 256.f, s2 = v.z * 256.f, s3 = v.w * 256.f;
    hf h0 = (hf)s0, h1 = (hf)s1, h2 = (hf)s2, h3 = (hf)s3;
    hf4 hv = {h0, h1, h2, h3};
    hf4 lv = {(hf)(s0 - (float)h0), (hf)(s1 - (float)h1),
              (hf)(s2 - (float)h2), (hf)(s3 - (float)h3)};
    const size_t d = (size_t)(m >> 4) * 32768 + (size_t)(k >> 5) * 512
                   + ((m & 15) << 5) + (k & 31);
    *(hf4*)(hi + d) = hv;
    *(hf4*)(lo + d) = lv;
}

// ---------------------------------------------------------------------------
// Streaming GEMM mainloop: LDS-free, fragments direct from panel layout.
// Wave tile 64x64 (4x4 of 16x16), block 128x128, K=2048, split x3.
// Register double-buffer uses CONSTANT indices only (R5 lesson: runtime
// buffer indices demote arrays to scratch -> GBs of spill traffic).
// ---------------------------------------------------------------------------
#define DECLARE_MAINLOOP \
    f32x4 acc[4][4]; \
    _Pragma("unroll") for (int i = 0; i < 4; ++i) \
    _Pragma("unroll") for (int j = 0; j < 4; ++j) acc[i][j] = {0.f,0.f,0.f,0.f}; \
    const size_t loff = (size_t)(fr * 32 + fq * 8); \
    const size_t a0 = (size_t)((bm + wm) >> 4) * 32768 + loff; \
    const size_t b0 = (size_t)((bn + wn) >> 4) * 32768 + loff; \
    hf8 Fah[2][4], Fal[2][4], Fbh[2][4], Fbl[2][4];

#define LOADSET(s, kb) do { \
    _Pragma("unroll") for (int t = 0; t < 4; ++t) { \
        Fah[s][t] = *(const hf8*)(Ah + a0 + (size_t)t * 32768 + (size_t)(kb) * 512); \
        Fal[s][t] = *(const hf8*)(Al + a0 + (size_t)t * 32768 + (size_t)(kb) * 512); \
        Fbh[s][t] = *(const hf8*)(Bh + b0 + (size_t)t * 32768 + (size_t)(kb) * 512); \
        Fbl[s][t] = *(const hf8*)(Bl + b0 + (size_t)t * 32768 + (size_t)(kb) * 512); \
    } } while (0)

#define MFMASET(s) do { \
    _Pragma("unroll") for (int i = 0; i < 4; ++i) \
    _Pragma("unroll") for (int j = 0; j < 4; ++j) { \
        acc[i][j] = MFMA16(Fah[s][i], Fbh[s][j], acc[i][j]); \
        acc[i][j] = MFMA16(Fah[s][i], Fbl[s][j], acc[i][j]); \
        acc[i][j] = MFMA16(Fal[s][i], Fbh[s][j], acc[i][j]); \
    } } while (0)

#define RUN_MAINLOOP \
    LOADSET(0, 0); \
    for (int kb = 0; kb < KB64; kb += 2) { \
        LOADSET(1, kb + 1); \
        MFMASET(0); \
        if (kb + 2 < KB64) LOADSET(0, kb + 2); \
        MFMASET(1); \
    }

// ---------------------------------------------------------------------------
// Fused Q/K/V projection. grid(24, 32): bx<16 -> Q (hi/lo), 16..19 -> K
// (hi/lo), 20..23 -> V (single fp16, transposed vT[d][MTOT]).
// ---------------------------------------------------------------------------
__global__ __launch_bounds__(256, 2)
void gemm_qkv(const hf* __restrict__ xh, const hf* __restrict__ xl,
              const hf* __restrict__ wqh, const hf* __restrict__ wql,
              const hf* __restrict__ wkh, const hf* __restrict__ wkl,
              const hf* __restrict__ wvh, const hf* __restrict__ wvl,
              hf* __restrict__ qh, hf* __restrict__ ql,
              hf* __restrict__ kh, hf* __restrict__ kl,
              hf* __restrict__ vT)
{
    const int tid = threadIdx.x;
    const int lane = tid & 63, wave = tid >> 6;
    const int fr = lane & 15, fq = lane >> 4;
    const int wm = (wave & 1) * 64, wn = (wave >> 1) * 64;
    const int bm = blockIdx.y * 128;
    const int bx = blockIdx.x;

    const hf *Bh, *Bl;
    hf *Oh = nullptr, *Ol = nullptr;
    int bn, Nout, mode;
    if (bx < 16)      { Bh = wqh; Bl = wql; bn = bx * 128;        Nout = HID;   Oh = qh; Ol = ql; mode = 1; }
    else if (bx < 20) { Bh = wkh; Bl = wkl; bn = (bx - 16) * 128; Nout = KVDIM; Oh = kh; Ol = kl; mode = 1; }
    else              { Bh = wvh; Bl = wvl; bn = (bx - 20) * 128; Nout = KVDIM; mode = 2; }

    const hf* Ah = xh; const hf* Al = xl;
    DECLARE_MAINLOOP
    RUN_MAINLOOP

    if (mode == 1) {
        const float scale = 32.f / 65536.f;
#pragma unroll
        for (int j = 0; j < 4; ++j) {
            const int col = bn + wn + j * 16 + fr;
#pragma unroll
            for (int i = 0; i < 4; ++i) {
                const int row0 = bm + wm + i * 16 + fq * 4;
#pragma unroll
                for (int r = 0; r < 4; ++r) {
                    const size_t idx = (size_t)(row0 + r) * Nout + col;
                    float v = acc[i][j][r] * scale;
                    hf h = (hf)v;
                    Oh[idx] = h;
                    Ol[idx] = (hf)(v - (float)h);
                }
            }
        }
    } else {
        const float scale = 1.f / 65536.f;
#pragma unroll
        for (int j = 0; j < 4; ++j) {
            const int col = bn + wn + j * 16 + fr;             // d index
#pragma unroll
            for (int i = 0; i < 4; ++i) {
                const int row0 = bm + wm + i * 16 + fq * 4;    // seq index
                hf4 pk = {(hf)(acc[i][j][0] * scale), (hf)(acc[i][j][1] * scale),
                          (hf)(acc[i][j][2] * scale), (hf)(acc[i][j][3] * scale)};
                *(hf4*)(vT + (size_t)col * MTOT + row0) = pk;
            }
        }
    }
}

// ---------------------------------------------------------------------------
// Output projection: out = (attn panels) @ Wo^T + bias, fp32 out.
// ---------------------------------------------------------------------------
__global__ __launch_bounds__(256, 2)
void gemm_out(const hf* __restrict__ Ah, const hf* __restrict__ Al,
              const hf* __restrict__ Bh, const hf* __restrict__ Bl,
              const float* __restrict__ bias, float* __restrict__ Cf)
{
    const int tid = threadIdx.x;
    const int lane = tid & 63, wave = tid >> 6;
    const int fr = lane & 15, fq = lane >> 4;
    const int wm = (wave & 1) * 64, wn = (wave >> 1) * 64;
    const int bm = blockIdx.y * 128, bn = blockIdx.x * 128;

    DECLARE_MAINLOOP
    RUN_MAINLOOP

    const float scale = 1.f / 65536.f;
#pragma unroll
    for (int j = 0; j < 4; ++j) {
        const int col = bn + wn + j * 16 + fr;
        const float bv = bias[col];
#pragma unroll
        for (int i = 0; i < 4; ++i) {
            const int row0 = bm + wm + i * 16 + fq * 4;
#pragma unroll
            for (int r = 0; r < 4; ++r)
                Cf[(size_t)(row0 + r) * HID + col] = acc[i][j][r] * scale + bv;
        }
    }
}

// ---------------------------------------------------------------------------
// Attention, S^T orientation, R3 structure + STATIC register K-prefetch.
// Block = 256 thr / 4 waves on 4 consecutive q-tiles of ONE head (waves share
// the K/V stream -> L1/L2 hits). Wave-private LDS P tile, NO __syncthreads.
// kv-loop is unrolled x2 so the two K fragment buffers (k0*, k1*) have
// compile-time indices only (R5 lesson: runtime-indexed register arrays get
// demoted to scratch -> GBs of spill traffic, 10x regression).
// ---------------------------------------------------------------------------
__global__ __launch_bounds__(256, 2)
void attn_st(const hf* __restrict__ Qhg, const hf* __restrict__ Qlg,
             const hf* __restrict__ Khg, const hf* __restrict__ Klg,
             const hf* __restrict__ Vtg,
             hf* __restrict__ Ohg, hf* __restrict__ Olg)
{
    __shared__ hf Ps[4][64][40];      // [wave][q-row][col chunk=32 + pad]
    const int tid  = threadIdx.x;
    const int lane = tid & 63, wave = tid >> 6;
    const int fr = lane & 15, fq = lane >> 4;
    const int hd = blockIdx.y, b = blockIdx.z;
    const int kvh = hd >> 2;
    const int qbase = blockIdx.x * 256 + wave * 64;
    const float SSCALE = 1.f / 8192.f;

    // persistent Q fragments (B-operand: n=q-row=fr, k=d=fq*8+u+32s)
    hf8 qfh[4][2], qfl[4][2];
#pragma unroll
    for (int nt = 0; nt < 4; ++nt) {
        const size_t rb = (size_t)(b * SEQ + qbase + nt * 16 + fr) * HID + hd * 64;
#pragma unroll
        for (int s = 0; s < 2; ++s) {
            qfh[nt][s] = *(const hf8*)(Qhg + rb + s * 32 + fq * 8);
            qfl[nt][s] = *(const hf8*)(Qlg + rb + s * 32 + fq * 8);
        }
    }

    f32x4 oacc[4][4];                 // O^T tiles [d-tile][q-tile]
#pragma unroll
    for (int i = 0; i < 4; ++i)
#pragma unroll
        for (int j = 0; j < 4; ++j) oacc[i][j] = {0.f, 0.f, 0.f, 0.f};
    float lsum[4] = {0.f, 0.f, 0.f, 0.f};

    const size_t kbase = (size_t)(b * SEQ) * KVDIM + kvh * 64;
    const size_t vbase = (size_t)(kvh * 64) * MTOT + (size_t)(b * SEQ);

    // two explicit K fragment buffers, constant indices only
    hf8 k0h[2][2], k0l[2][2], k1h[2][2], k1l[2][2];   // [mt][s]

#define LOADK(KH, KL, t0) do { \
    _Pragma("unroll") for (int mt = 0; mt < 2; ++mt) { \
        const size_t kr = kbase + (size_t)((t0) + mt * 16 + fr) * KVDIM; \
        _Pragma("unroll") for (int s = 0; s < 2; ++s) { \
            KH[mt][s] = *(const hf8*)(Khg + kr + s * 32 + fq * 8); \
            KL[mt][s] = *(const hf8*)(Klg + kr + s * 32 + fq * 8); \
        } } } while (0)

#define CHUNK_BODY(KH, KL, t0) do { \
    hf8 vfr[4]; \
    _Pragma("unroll") for (int dt = 0; dt < 4; ++dt) \
        vfr[dt] = *(const hf8*)(Vtg + vbase + (size_t)(dt * 16 + fr) * MTOT \
                                + (t0) + fq * 8); \
    f32x4 sacc[2][4]; \
    _Pragma("unroll") for (int mt = 0; mt < 2; ++mt) \
    _Pragma("unroll") for (int nt = 0; nt < 4; ++nt) sacc[mt][nt] = {0.f,0.f,0.f,0.f}; \
    _Pragma("unroll") for (int mt = 0; mt < 2; ++mt) \
    _Pragma("unroll") for (int nt = 0; nt < 4; ++nt) \
    _Pragma("unroll") for (int s = 0; s < 2; ++s) { \
        sacc[mt][nt] = MFMA16(KH[mt][s], qfh[nt][s], sacc[mt][nt]); \
        sacc[mt][nt] = MFMA16(KH[mt][s], qfl[nt][s], sacc[mt][nt]); \
        sacc[mt][nt] = MFMA16(KL[mt][s], qfh[nt][s], sacc[mt][nt]); \
    } \
    _Pragma("unroll") for (int mt = 0; mt < 2; ++mt) \
    _Pragma("unroll") for (int nt = 0; nt < 4; ++nt) { \
        float p0 = __expf(sacc[mt][nt][0] * SSCALE); \
        float p1 = __expf(sacc[mt][nt][1] * SSCALE); \
        float p2 = __expf(sacc[mt][nt][2] * SSCALE); \
        float p3 = __expf(sacc[mt][nt][3] * SSCALE); \
        lsum[nt] += (p0 + p1) + (p2 + p3); \
        hf4 pk = {(hf)p0, (hf)p1, (hf)p2, (hf)p3}; \
        *(hf4*)&Ps[wave][nt * 16 + fr][mt * 16 + fq * 4] = pk; \
    } \
    hf8 pa[4]; \
    _Pragma("unroll") for (int qt = 0; qt < 4; ++qt) \
        pa[qt] = *(const hf8*)&Ps[wave][qt * 16 + fr][fq * 8]; \
    _Pragma("unroll") for (int dt = 0; dt < 4; ++dt) \
    _Pragma("unroll") for (int qt = 0; qt < 4; ++qt) \
        oacc[dt][qt] = MFMA16(vfr[dt], pa[qt], oacc[dt][qt]); \
} while (0)

    LOADK(k0h, k0l, 0);
    for (int t0 = 0; t0 < SEQ; t0 += 64) {
        LOADK(k1h, k1l, t0 + 32);          // prefetch odd chunk
        CHUNK_BODY(k0h, k0l, t0);          // compute even chunk
        if (t0 + 64 < SEQ) LOADK(k0h, k0l, t0 + 64);   // prefetch next even
        CHUNK_BODY(k1h, k1l, t0 + 32);     // compute odd chunk
    }
#undef LOADK
#undef CHUNK_BODY

#pragma unroll
    for (int qt = 0; qt < 4; ++qt) {
        lsum[qt] += __shfl_xor(lsum[qt], 16, 64);
        lsum[qt] += __shfl_xor(lsum[qt], 32, 64);
    }

    // epilogue: attn = O/l, store split(256*attn) in A-PANEL layout.
    // lane element: q = qbase+qt*16+fr, k(hidden) = hd*64 + dt*16 + fq*4 + e
#pragma unroll
    for (int qt = 0; qt < 4; ++qt) {
        const float inv = 256.f / lsum[qt];
        const int pq = ((b * SEQ + qbase) >> 4) + qt;
#pragma unroll
        for (int dt = 0; dt < 4; ++dt) {
            float o0 = oacc[dt][qt][0] * inv, o1 = oacc[dt][qt][1] * inv;
            float o2 = oacc[dt][qt][2] * inv, o3 = oacc[dt][qt][3] * inv;
            hf h0 = (hf)o0, h1 = (hf)o1, h2 = (hf)o2, h3 = (hf)o3;
            hf4 hv = {h0, h1, h2, h3};
            hf4 lv = {(hf)(o0 - (float)h0), (hf)(o1 - (float)h1),
                      (hf)(o2 - (float)h2), (hf)(o3 - (float)h3)};
            const int kb = hd * 2 + (dt >> 1);
            const size_t d = (size_t)pq * 32768 + (size_t)kb * 512
                           + fr * 32 + (dt & 1) * 16 + fq * 4;
            *(hf4*)(Ohg + d) = hv;
            *(hf4*)(Olg + d) = lv;
        }
    }
}

// ---------------------------------------------------------------------------
extern "C" void kernel_launch(void* const* d_in, const int* in_sizes, int n_in,
                              void* d_out, int out_size, void* d_ws, size_t ws_size,
                              hipStream_t stream)
{
    const float* x  = (const float*)d_in[0];
    const float* Wq = (const float*)d_in[1];
    const float* Wk = (const float*)d_in[2];
    const float* Wv = (const float*)d_in[3];
    const float* Wo = (const float*)d_in[4];
    const float* bo = (const float*)d_in[5];
    float* out = (float*)d_out;
    (void)in_sizes; (void)n_in; (void)out_size; (void)ws_size;

    // workspace (halves), 116 MB. xh/xl reused as attn-output panels.
    hf* p = (hf*)d_ws;
    hf* xh  = p; p += (size_t)MTOT * HID;
    hf* xl  = p; p += (size_t)MTOT * HID;
    hf* qh  = p; p += (size_t)MTOT * HID;
    hf* ql  = p; p += (size_t)MTOT * HID;
    hf* kh  = p; p += (size_t)MTOT * KVDIM;
    hf* kl  = p; p += (size_t)MTOT * KVDIM;
    hf* vT  = p; p += (size_t)MTOT * KVDIM;
    hf* wqh = p; p += (size_t)HID * HID;
    hf* wql = p; p += (size_t)HID * HID;
    hf* wkh = p; p += (size_t)KVDIM * HID;
    hf* wkl = p; p += (size_t)KVDIM * HID;
    hf* wvh = p; p += (size_t)KVDIM * HID;
    hf* wvl = p; p += (size_t)KVDIM * HID;
    hf* woh = p; p += (size_t)HID * HID;
    hf* wol = p; p += (size_t)HID * HID;

    // prep: split into panel layout (all K = 2048)
    split_panel<<<(MTOT * HID) / 1024, 256, 0, stream>>>(x,  xh,  xl,  MTOT * HID);
    split_panel<<<(HID * HID)  / 1024, 256, 0, stream>>>(Wq, wqh, wql, HID * HID);
    split_panel<<<(KVDIM * HID)/ 1024, 256, 0, stream>>>(Wk, wkh, wkl, KVDIM * HID);
    split_panel<<<(KVDIM * HID)/ 1024, 256, 0, stream>>>(Wv, wvh, wvl, KVDIM * HID);
    split_panel<<<(HID * HID)  / 1024, 256, 0, stream>>>(Wo, woh, wol, HID * HID);

    gemm_qkv<<<dim3(24, MTOT / 128), 256, 0, stream>>>(
        xh, xl, wqh, wql, wkh, wkl, wvh, wvl, qh, ql, kh, kl, vT);

    attn_st<<<dim3(SEQ / 256, NHEADS, BATCH), 256, 0, stream>>>(
        qh, ql, kh, kl, vT, xh, xl);

    gemm_out<<<dim3(HID / 128, MTOT / 128), 256, 0, stream>>>(
        xh, xl, woh, wol, bo, out);
}

// Round 7
// 602.704 us; speedup vs baseline: 15.0407x; 1.0809x over previous
//
#include <hip/hip_runtime.h>

#define HID 2048
#define NHEADS 32
#define NKV 8
#define HEADD 64
#define BATCH 2
#define SEQ 2048
#define MTOT (BATCH*SEQ)      // 4096
#define KVDIM (NKV*HEADD)     // 512
#define KB64 (HID/32)         // 64 k-blocks

typedef _Float16 hf;
typedef hf hf8 __attribute__((ext_vector_type(8)));
typedef hf hf4 __attribute__((ext_vector_type(4)));
typedef float f32x4 __attribute__((ext_vector_type(4)));

#define MFMA16(a,b,c) __builtin_amdgcn_mfma_f32_16x16x32_f16(a, b, c, 0, 0, 0)

// Panel layout (halves): addr(m,k) = ((m>>4)*(K/32) + (k>>5))*512 + (m&15)*32 + (k&31)
// K = 2048 always -> (m>>4)*64*512 = (m>>4)*32768.

// ---------------------------------------------------------------------------
// Fused split: all five fp32 tensors -> hi/lo fp16 (x256) panels, one launch.
// Block ranges (1024 elems each): x 8192 | Wq 4096 | Wk 1024 | Wv 1024 | Wo 4096
// ---------------------------------------------------------------------------
__global__ __launch_bounds__(256)
void split_all(const float* __restrict__ x,  const float* __restrict__ Wq,
               const float* __restrict__ Wk, const float* __restrict__ Wv,
               const float* __restrict__ Wo,
               hf* __restrict__ xh,  hf* __restrict__ xl,
               hf* __restrict__ wqh, hf* __restrict__ wql,
               hf* __restrict__ wkh, hf* __restrict__ wkl,
               hf* __restrict__ wvh, hf* __restrict__ wvl,
               hf* __restrict__ woh, hf* __restrict__ wol)
{
    const int bid = blockIdx.x;
    const float* src; hf *hi, *lo; int base;
    if (bid < 8192)       { src = x;  hi = xh;  lo = xl;  base = bid; }
    else if (bid < 12288) { src = Wq; hi = wqh; lo = wql; base = bid - 8192; }
    else if (bid < 13312) { src = Wk; hi = wkh; lo = wkl; base = bid - 12288; }
    else if (bid < 14336) { src = Wv; hi = wvh; lo = wvl; base = bid - 13312; }
    else                  { src = Wo; hi = woh; lo = wol; base = bid - 14336; }

    const int idx = (base * 256 + threadIdx.x) * 4;
    const int m = idx >> 11, k = idx & 2047;
    float4 v = *(const float4*)(src + idx);
    float s0 = v.x * 256.f, s1 = v.y * 256.f, s2 = v.z * 256.f, s3 = v.w * 256.f;
    hf h0 = (hf)s0, h1 = (hf)s1, h2 = (hf)s2, h3 = (hf)s3;
    hf4 hv = {h0, h1, h2, h3};
    hf4 lv = {(hf)(s0 - (float)h0), (hf)(s1 - (float)h1),
              (hf)(s2 - (float)h2), (hf)(s3 - (float)h3)};
    const size_t d = (size_t)(m >> 4) * 32768 + (size_t)(k >> 5) * 512
                   + ((m & 15) << 5) + (k & 31);
    *(hf4*)(hi + d) = hv;
    *(hf4*)(lo + d) = lv;
}

// ---------------------------------------------------------------------------
// Streaming GEMM mainloop: LDS-free, fragments direct from panel layout.
// Wave tile 64x64 (4x4 of 16x16), block 128x128, K=2048, split x3.
// sched_group_barrier pins AITER-style interleave (2 VMEM-read : 6 MFMA)
// so the compiler cannot sink the prefetch loads to their consumers
// (R6 post-mortem: VGPR=100 proved the x2 pipeline was collapsed,
// MfmaUtil 24% from serialized load->wait->compute rounds).
// ---------------------------------------------------------------------------
#define DECLARE_MAINLOOP \
    f32x4 acc[4][4]; \
    _Pragma("unroll") for (int i = 0; i < 4; ++i) \
    _Pragma("unroll") for (int j = 0; j < 4; ++j) acc[i][j] = {0.f,0.f,0.f,0.f}; \
    const size_t loff = (size_t)(fr * 32 + fq * 8); \
    const size_t a0 = (size_t)((bm + wm) >> 4) * 32768 + loff; \
    const size_t b0 = (size_t)((bn + wn) >> 4) * 32768 + loff; \
    hf8 Fah[2][4], Fal[2][4], Fbh[2][4], Fbl[2][4];

#define LOADSET(s, kb) do { \
    _Pragma("unroll") for (int t = 0; t < 4; ++t) { \
        Fah[s][t] = *(const hf8*)(Ah + a0 + (size_t)t * 32768 + (size_t)(kb) * 512); \
        Fal[s][t] = *(const hf8*)(Al + a0 + (size_t)t * 32768 + (size_t)(kb) * 512); \
        Fbh[s][t] = *(const hf8*)(Bh + b0 + (size_t)t * 32768 + (size_t)(kb) * 512); \
        Fbl[s][t] = *(const hf8*)(Bl + b0 + (size_t)t * 32768 + (size_t)(kb) * 512); \
    } } while (0)

#define MFMASET(s) do { \
    _Pragma("unroll") for (int i = 0; i < 4; ++i) \
    _Pragma("unroll") for (int j = 0; j < 4; ++j) { \
        acc[i][j] = MFMA16(Fah[s][i], Fbh[s][j], acc[i][j]); \
        acc[i][j] = MFMA16(Fah[s][i], Fbl[s][j], acc[i][j]); \
        acc[i][j] = MFMA16(Fal[s][i], Fbh[s][j], acc[i][j]); \
    } } while (0)

// body: 32 VMEM reads + 96 MFMA  -> 16 x (2 loads : 6 mfma)
#define SCHED_BODY \
    _Pragma("unroll") for (int g = 0; g < 16; ++g) { \
        __builtin_amdgcn_sched_group_barrier(0x020, 2, 0); \
        __builtin_amdgcn_sched_group_barrier(0x008, 6, 0); \
    }
// tail: 16 VMEM reads + 96 MFMA -> 8 x (2:6) then pure MFMA
#define SCHED_TAIL \
    _Pragma("unroll") for (int g = 0; g < 8; ++g) { \
        __builtin_amdgcn_sched_group_barrier(0x020, 2, 0); \
        __builtin_amdgcn_sched_group_barrier(0x008, 6, 0); \
    } \
    __builtin_amdgcn_sched_group_barrier(0x008, 48, 0);

#define RUN_MAINLOOP \
    LOADSET(0, 0); \
    for (int kb = 0; kb < KB64 - 2; kb += 2) { \
        LOADSET(1, kb + 1); \
        MFMASET(0); \
        LOADSET(0, kb + 2); \
        MFMASET(1); \
        SCHED_BODY \
    } \
    LOADSET(1, KB64 - 1); \
    MFMASET(0); \
    MFMASET(1); \
    SCHED_TAIL

// ---------------------------------------------------------------------------
// Fused Q/K/V projection. grid(24, 32): bx<16 -> Q (hi/lo), 16..19 -> K
// (hi/lo), 20..23 -> V (single fp16, transposed vT[d][MTOT]).
// ---------------------------------------------------------------------------
__global__ __launch_bounds__(256, 2)
void gemm_qkv(const hf* __restrict__ xh, const hf* __restrict__ xl,
              const hf* __restrict__ wqh, const hf* __restrict__ wql,
              const hf* __restrict__ wkh, const hf* __restrict__ wkl,
              const hf* __restrict__ wvh, const hf* __restrict__ wvl,
              hf* __restrict__ qh, hf* __restrict__ ql,
              hf* __restrict__ kh, hf* __restrict__ kl,
              hf* __restrict__ vT)
{
    const int tid = threadIdx.x;
    const int lane = tid & 63, wave = tid >> 6;
    const int fr = lane & 15, fq = lane >> 4;
    const int wm = (wave & 1) * 64, wn = (wave >> 1) * 64;
    const int bm = blockIdx.y * 128;
    const int bx = blockIdx.x;

    const hf *Bh, *Bl;
    hf *Oh = nullptr, *Ol = nullptr;
    int bn, Nout, mode;
    if (bx < 16)      { Bh = wqh; Bl = wql; bn = bx * 128;        Nout = HID;   Oh = qh; Ol = ql; mode = 1; }
    else if (bx < 20) { Bh = wkh; Bl = wkl; bn = (bx - 16) * 128; Nout = KVDIM; Oh = kh; Ol = kl; mode = 1; }
    else              { Bh = wvh; Bl = wvl; bn = (bx - 20) * 128; Nout = KVDIM; mode = 2; }

    const hf* Ah = xh; const hf* Al = xl;
    DECLARE_MAINLOOP
    RUN_MAINLOOP

    if (mode == 1) {
        const float scale = 32.f / 65536.f;
#pragma unroll
        for (int j = 0; j < 4; ++j) {
            const int col = bn + wn + j * 16 + fr;
#pragma unroll
            for (int i = 0; i < 4; ++i) {
                const int row0 = bm + wm + i * 16 + fq * 4;
#pragma unroll
                for (int r = 0; r < 4; ++r) {
                    const size_t idx = (size_t)(row0 + r) * Nout + col;
                    float v = acc[i][j][r] * scale;
                    hf h = (hf)v;
                    Oh[idx] = h;
                    Ol[idx] = (hf)(v - (float)h);
                }
            }
        }
    } else {
        const float scale = 1.f / 65536.f;
#pragma unroll
        for (int j = 0; j < 4; ++j) {
            const int col = bn + wn + j * 16 + fr;             // d index
#pragma unroll
            for (int i = 0; i < 4; ++i) {
                const int row0 = bm + wm + i * 16 + fq * 4;    // seq index
                hf4 pk = {(hf)(acc[i][j][0] * scale), (hf)(acc[i][j][1] * scale),
                          (hf)(acc[i][j][2] * scale), (hf)(acc[i][j][3] * scale)};
                *(hf4*)(vT + (size_t)col * MTOT + row0) = pk;
            }
        }
    }
}

// ---------------------------------------------------------------------------
// Output projection: out = (attn panels) @ Wo^T + bias, fp32 out.
// ---------------------------------------------------------------------------
__global__ __launch_bounds__(256, 2)
void gemm_out(const hf* __restrict__ Ah, const hf* __restrict__ Al,
              const hf* __restrict__ Bh, const hf* __restrict__ Bl,
              const float* __restrict__ bias, float* __restrict__ Cf)
{
    const int tid = threadIdx.x;
    const int lane = tid & 63, wave = tid >> 6;
    const int fr = lane & 15, fq = lane >> 4;
    const int wm = (wave & 1) * 64, wn = (wave >> 1) * 64;
    const int bm = blockIdx.y * 128, bn = blockIdx.x * 128;

    DECLARE_MAINLOOP
    RUN_MAINLOOP

    const float scale = 1.f / 65536.f;
#pragma unroll
    for (int j = 0; j < 4; ++j) {
        const int col = bn + wn + j * 16 + fr;
        const float bv = bias[col];
#pragma unroll
        for (int i = 0; i < 4; ++i) {
            const int row0 = bm + wm + i * 16 + fq * 4;
#pragma unroll
            for (int r = 0; r < 4; ++r)
                Cf[(size_t)(row0 + r) * HID + col] = acc[i][j][r] * scale + bv;
        }
    }
}

// ---------------------------------------------------------------------------
// Attention, S^T orientation, R3 structure + STATIC register K-prefetch
// (unchanged from R6 — ~42% of its MFMA floor, best kernel in the pipeline).
// ---------------------------------------------------------------------------
__global__ __launch_bounds__(256, 2)
void attn_st(const hf* __restrict__ Qhg, const hf* __restrict__ Qlg,
             const hf* __restrict__ Khg, const hf* __restrict__ Klg,
             const hf* __restrict__ Vtg,
             hf* __restrict__ Ohg, hf* __restrict__ Olg)
{
    __shared__ hf Ps[4][64][40];      // [wave][q-row][col chunk=32 + pad]
    const int tid  = threadIdx.x;
    const int lane = tid & 63, wave = tid >> 6;
    const int fr = lane & 15, fq = lane >> 4;
    const int hd = blockIdx.y, b = blockIdx.z;
    const int kvh = hd >> 2;
    const int qbase = blockIdx.x * 256 + wave * 64;
    const float SSCALE = 1.f / 8192.f;

    // persistent Q fragments (B-operand: n=q-row=fr, k=d=fq*8+u+32s)
    hf8 qfh[4][2], qfl[4][2];
#pragma unroll
    for (int nt = 0; nt < 4; ++nt) {
        const size_t rb = (size_t)(b * SEQ + qbase + nt * 16 + fr) * HID + hd * 64;
#pragma unroll
        for (int s = 0; s < 2; ++s) {
            qfh[nt][s] = *(const hf8*)(Qhg + rb + s * 32 + fq * 8);
            qfl[nt][s] = *(const hf8*)(Qlg + rb + s * 32 + fq * 8);
        }
    }

    f32x4 oacc[4][4];                 // O^T tiles [d-tile][q-tile]
#pragma unroll
    for (int i = 0; i < 4; ++i)
#pragma unroll
        for (int j = 0; j < 4; ++j) oacc[i][j] = {0.f, 0.f, 0.f, 0.f};
    float lsum[4] = {0.f, 0.f, 0.f, 0.f};

    const size_t kbase = (size_t)(b * SEQ) * KVDIM + kvh * 64;
    const size_t vbase = (size_t)(kvh * 64) * MTOT + (size_t)(b * SEQ);

    // two explicit K fragment buffers, constant indices only
    hf8 k0h[2][2], k0l[2][2], k1h[2][2], k1l[2][2];   // [mt][s]

#define LOADK(KH, KL, t0) do { \
    _Pragma("unroll") for (int mt = 0; mt < 2; ++mt) { \
        const size_t kr = kbase + (size_t)((t0) + mt * 16 + fr) * KVDIM; \
        _Pragma("unroll") for (int s = 0; s < 2; ++s) { \
            KH[mt][s] = *(const hf8*)(Khg + kr + s * 32 + fq * 8); \
            KL[mt][s] = *(const hf8*)(Klg + kr + s * 32 + fq * 8); \
        } } } while (0)

#define CHUNK_BODY(KH, KL, t0) do { \
    hf8 vfr[4]; \
    _Pragma("unroll") for (int dt = 0; dt < 4; ++dt) \
        vfr[dt] = *(const hf8*)(Vtg + vbase + (size_t)(dt * 16 + fr) * MTOT \
                                + (t0) + fq * 8); \
    f32x4 sacc[2][4]; \
    _Pragma("unroll") for (int mt = 0; mt < 2; ++mt) \
    _Pragma("unroll") for (int nt = 0; nt < 4; ++nt) sacc[mt][nt] = {0.f,0.f,0.f,0.f}; \
    _Pragma("unroll") for (int mt = 0; mt < 2; ++mt) \
    _Pragma("unroll") for (int nt = 0; nt < 4; ++nt) \
    _Pragma("unroll") for (int s = 0; s < 2; ++s) { \
        sacc[mt][nt] = MFMA16(KH[mt][s], qfh[nt][s], sacc[mt][nt]); \
        sacc[mt][nt] = MFMA16(KH[mt][s], qfl[nt][s], sacc[mt][nt]); \
        sacc[mt][nt] = MFMA16(KL[mt][s], qfh[nt][s], sacc[mt][nt]); \
    } \
    _Pragma("unroll") for (int mt = 0; mt < 2; ++mt) \
    _Pragma("unroll") for (int nt = 0; nt < 4; ++nt) { \
        float p0 = __expf(sacc[mt][nt][0] * SSCALE); \
        float p1 = __expf(sacc[mt][nt][1] * SSCALE); \
        float p2 = __expf(sacc[mt][nt][2] * SSCALE); \
        float p3 = __expf(sacc[mt][nt][3] * SSCALE); \
        lsum[nt] += (p0 + p1) + (p2 + p3); \
        hf4 pk = {(hf)p0, (hf)p1, (hf)p2, (hf)p3}; \
        *(hf4*)&Ps[wave][nt * 16 + fr][mt * 16 + fq * 4] = pk; \
    } \
    hf8 pa[4]; \
    _Pragma("unroll") for (int qt = 0; qt < 4; ++qt) \
        pa[qt] = *(const hf8*)&Ps[wave][qt * 16 + fr][fq * 8]; \
    _Pragma("unroll") for (int dt = 0; dt < 4; ++dt) \
    _Pragma("unroll") for (int qt = 0; qt < 4; ++qt) \
        oacc[dt][qt] = MFMA16(vfr[dt], pa[qt], oacc[dt][qt]); \
} while (0)

    LOADK(k0h, k0l, 0);
    for (int t0 = 0; t0 < SEQ; t0 += 64) {
        LOADK(k1h, k1l, t0 + 32);          // prefetch odd chunk
        CHUNK_BODY(k0h, k0l, t0);          // compute even chunk
        if (t0 + 64 < SEQ) LOADK(k0h, k0l, t0 + 64);   // prefetch next even
        CHUNK_BODY(k1h, k1l, t0 + 32);     // compute odd chunk
    }
#undef LOADK
#undef CHUNK_BODY

#pragma unroll
    for (int qt = 0; qt < 4; ++qt) {
        lsum[qt] += __shfl_xor(lsum[qt], 16, 64);
        lsum[qt] += __shfl_xor(lsum[qt], 32, 64);
    }

    // epilogue: attn = O/l, store split(256*attn) in A-PANEL layout.
#pragma unroll
    for (int qt = 0; qt < 4; ++qt) {
        const float inv = 256.f / lsum[qt];
        const int pq = ((b * SEQ + qbase) >> 4) + qt;
#pragma unroll
        for (int dt = 0; dt < 4; ++dt) {
            float o0 = oacc[dt][qt][0] * inv, o1 = oacc[dt][qt][1] * inv;
            float o2 = oacc[dt][qt][2] * inv, o3 = oacc[dt][qt][3] * inv;
            hf h0 = (hf)o0, h1 = (hf)o1, h2 = (hf)o2, h3 = (hf)o3;
            hf4 hv = {h0, h1, h2, h3};
            hf4 lv = {(hf)(o0 - (float)h0), (hf)(o1 - (float)h1),
                      (hf)(o2 - (float)h2), (hf)(o3 - (float)h3)};
            const int kb = hd * 2 + (dt >> 1);
            const size_t d = (size_t)pq * 32768 + (size_t)kb * 512
                           + fr * 32 + (dt & 1) * 16 + fq * 4;
            *(hf4*)(Ohg + d) = hv;
            *(hf4*)(Olg + d) = lv;
        }
    }
}

// ---------------------------------------------------------------------------
extern "C" void kernel_launch(void* const* d_in, const int* in_sizes, int n_in,
                              void* d_out, int out_size, void* d_ws, size_t ws_size,
                              hipStream_t stream)
{
    const float* x  = (const float*)d_in[0];
    const float* Wq = (const float*)d_in[1];
    const float* Wk = (const float*)d_in[2];
    const float* Wv = (const float*)d_in[3];
    const float* Wo = (const float*)d_in[4];
    const float* bo = (const float*)d_in[5];
    float* out = (float*)d_out;
    (void)in_sizes; (void)n_in; (void)out_size; (void)ws_size;

    // workspace (halves), 116 MB. xh/xl reused as attn-output panels.
    hf* p = (hf*)d_ws;
    hf* xh  = p; p += (size_t)MTOT * HID;
    hf* xl  = p; p += (size_t)MTOT * HID;
    hf* qh  = p; p += (size_t)MTOT * HID;
    hf* ql  = p; p += (size_t)MTOT * HID;
    hf* kh  = p; p += (size_t)MTOT * KVDIM;
    hf* kl  = p; p += (size_t)MTOT * KVDIM;
    hf* vT  = p; p += (size_t)MTOT * KVDIM;
    hf* wqh = p; p += (size_t)HID * HID;
    hf* wql = p; p += (size_t)HID * HID;
    hf* wkh = p; p += (size_t)KVDIM * HID;
    hf* wkl = p; p += (size_t)KVDIM * HID;
    hf* wvh = p; p += (size_t)KVDIM * HID;
    hf* wvl = p; p += (size_t)KVDIM * HID;
    hf* woh = p; p += (size_t)HID * HID;
    hf* wol = p; p += (size_t)HID * HID;

    // prep: split everything into panel layout, single launch
    split_all<<<18432, 256, 0, stream>>>(x, Wq, Wk, Wv, Wo,
        xh, xl, wqh, wql, wkh, wkl, wvh, wvl, woh, wol);

    gemm_qkv<<<dim3(24, MTOT / 128), 256, 0, stream>>>(
        xh, xl, wqh, wql, wkh, wkl, wvh, wvl, qh, ql, kh, kl, vT);

    attn_st<<<dim3(SEQ / 256, NHEADS, BATCH), 256, 0, stream>>>(
        qh, ql, kh, kl, vT, xh, xl);

    gemm_out<<<dim3(HID / 128, MTOT / 128), 256, 0, stream>>>(
        xh, xl, woh, wol, bo, out);
}

// Round 8
// 599.600 us; speedup vs baseline: 15.1186x; 1.0052x over previous
//
#include <hip/hip_runtime.h>

#define HID 2048
#define NHEADS 32
#define NKV 8
#define HEADD 64
#define BATCH 2
#define SEQ 2048
#define MTOT (BATCH*SEQ)      // 4096
#define KVDIM (NKV*HEADD)     // 512
#define KB64 (HID/32)         // 64 k-blocks

typedef _Float16 hf;
typedef hf hf8 __attribute__((ext_vector_type(8)));
typedef hf hf4 __attribute__((ext_vector_type(4)));
typedef float f32x4 __attribute__((ext_vector_type(4)));
typedef int iv2 __attribute__((ext_vector_type(2)));
typedef int iv4 __attribute__((ext_vector_type(4)));

#define MFMA16(a,b,c) __builtin_amdgcn_mfma_f32_16x16x32_f16(a, b, c, 0, 0, 0)

// pack two f32 -> one VGPR of 2xfp16 (v_cvt_pkrtz_f16_f32, single inst)
static __device__ __forceinline__ int pk2(float a, float b) {
    return __builtin_bit_cast(int, __builtin_amdgcn_cvt_pkrtz(a, b));
}

// Panel layout (halves): addr(m,k) = ((m>>4)*(K/32) + (k>>5))*512 + (m&15)*32 + (k&31)

// ---------------------------------------------------------------------------
// Fused split: all five fp32 tensors -> hi/lo fp16 (x256) panels, one launch.
// ---------------------------------------------------------------------------
__global__ __launch_bounds__(256)
void split_all(const float* __restrict__ x,  const float* __restrict__ Wq,
               const float* __restrict__ Wk, const float* __restrict__ Wv,
               const float* __restrict__ Wo,
               hf* __restrict__ xh,  hf* __restrict__ xl,
               hf* __restrict__ wqh, hf* __restrict__ wql,
               hf* __restrict__ wkh, hf* __restrict__ wkl,
               hf* __restrict__ wvh, hf* __restrict__ wvl,
               hf* __restrict__ woh, hf* __restrict__ wol)
{
    const int bid = blockIdx.x;
    const float* src; hf *hi, *lo; int base;
    if (bid < 8192)       { src = x;  hi = xh;  lo = xl;  base = bid; }
    else if (bid < 12288) { src = Wq; hi = wqh; lo = wql; base = bid - 8192; }
    else if (bid < 13312) { src = Wk; hi = wkh; lo = wkl; base = bid - 12288; }
    else if (bid < 14336) { src = Wv; hi = wvh; lo = wvl; base = bid - 13312; }
    else                  { src = Wo; hi = woh; lo = wol; base = bid - 14336; }

    const int idx = (base * 256 + threadIdx.x) * 4;
    const int m = idx >> 11, k = idx & 2047;
    float4 v = *(const float4*)(src + idx);
    float s0 = v.x * 256.f, s1 = v.y * 256.f, s2 = v.z * 256.f, s3 = v.w * 256.f;
    hf h0 = (hf)s0, h1 = (hf)s1, h2 = (hf)s2, h3 = (hf)s3;
    hf4 hv = {h0, h1, h2, h3};
    hf4 lv = {(hf)(s0 - (float)h0), (hf)(s1 - (float)h1),
              (hf)(s2 - (float)h2), (hf)(s3 - (float)h3)};
    const size_t d = (size_t)(m >> 4) * 32768 + (size_t)(k >> 5) * 512
                   + ((m & 15) << 5) + (k & 31);
    *(hf4*)(hi + d) = hv;
    *(hf4*)(lo + d) = lv;
}

// ---------------------------------------------------------------------------
// Streaming GEMM mainloop (unchanged from R7): LDS-free + sched_group_barrier
// pinned 2 VMEM : 6 MFMA interleave.
// ---------------------------------------------------------------------------
#define DECLARE_MAINLOOP \
    f32x4 acc[4][4]; \
    _Pragma("unroll") for (int i = 0; i < 4; ++i) \
    _Pragma("unroll") for (int j = 0; j < 4; ++j) acc[i][j] = {0.f,0.f,0.f,0.f}; \
    const size_t loff = (size_t)(fr * 32 + fq * 8); \
    const size_t a0 = (size_t)((bm + wm) >> 4) * 32768 + loff; \
    const size_t b0 = (size_t)((bn + wn) >> 4) * 32768 + loff; \
    hf8 Fah[2][4], Fal[2][4], Fbh[2][4], Fbl[2][4];

#define LOADSET(s, kb) do { \
    _Pragma("unroll") for (int t = 0; t < 4; ++t) { \
        Fah[s][t] = *(const hf8*)(Ah + a0 + (size_t)t * 32768 + (size_t)(kb) * 512); \
        Fal[s][t] = *(const hf8*)(Al + a0 + (size_t)t * 32768 + (size_t)(kb) * 512); \
        Fbh[s][t] = *(const hf8*)(Bh + b0 + (size_t)t * 32768 + (size_t)(kb) * 512); \
        Fbl[s][t] = *(const hf8*)(Bl + b0 + (size_t)t * 32768 + (size_t)(kb) * 512); \
    } } while (0)

#define MFMASET(s) do { \
    _Pragma("unroll") for (int i = 0; i < 4; ++i) \
    _Pragma("unroll") for (int j = 0; j < 4; ++j) { \
        acc[i][j] = MFMA16(Fah[s][i], Fbh[s][j], acc[i][j]); \
        acc[i][j] = MFMA16(Fah[s][i], Fbl[s][j], acc[i][j]); \
        acc[i][j] = MFMA16(Fal[s][i], Fbh[s][j], acc[i][j]); \
    } } while (0)

#define SCHED_BODY \
    _Pragma("unroll") for (int g = 0; g < 16; ++g) { \
        __builtin_amdgcn_sched_group_barrier(0x020, 2, 0); \
        __builtin_amdgcn_sched_group_barrier(0x008, 6, 0); \
    }
#define SCHED_TAIL \
    _Pragma("unroll") for (int g = 0; g < 8; ++g) { \
        __builtin_amdgcn_sched_group_barrier(0x020, 2, 0); \
        __builtin_amdgcn_sched_group_barrier(0x008, 6, 0); \
    } \
    __builtin_amdgcn_sched_group_barrier(0x008, 48, 0);

#define RUN_MAINLOOP \
    LOADSET(0, 0); \
    for (int kb = 0; kb < KB64 - 2; kb += 2) { \
        LOADSET(1, kb + 1); \
        MFMASET(0); \
        LOADSET(0, kb + 2); \
        MFMASET(1); \
        SCHED_BODY \
    } \
    LOADSET(1, KB64 - 1); \
    MFMASET(0); \
    MFMASET(1); \
    SCHED_TAIL

// ---------------------------------------------------------------------------
// Fused Q/K/V projection (unchanged from R7).
// ---------------------------------------------------------------------------
__global__ __launch_bounds__(256, 2)
void gemm_qkv(const hf* __restrict__ xh, const hf* __restrict__ xl,
              const hf* __restrict__ wqh, const hf* __restrict__ wql,
              const hf* __restrict__ wkh, const hf* __restrict__ wkl,
              const hf* __restrict__ wvh, const hf* __restrict__ wvl,
              hf* __restrict__ qh, hf* __restrict__ ql,
              hf* __restrict__ kh, hf* __restrict__ kl,
              hf* __restrict__ vT)
{
    const int tid = threadIdx.x;
    const int lane = tid & 63, wave = tid >> 6;
    const int fr = lane & 15, fq = lane >> 4;
    const int wm = (wave & 1) * 64, wn = (wave >> 1) * 64;
    const int bm = blockIdx.y * 128;
    const int bx = blockIdx.x;

    const hf *Bh, *Bl;
    hf *Oh = nullptr, *Ol = nullptr;
    int bn, Nout, mode;
    if (bx < 16)      { Bh = wqh; Bl = wql; bn = bx * 128;        Nout = HID;   Oh = qh; Ol = ql; mode = 1; }
    else if (bx < 20) { Bh = wkh; Bl = wkl; bn = (bx - 16) * 128; Nout = KVDIM; Oh = kh; Ol = kl; mode = 1; }
    else              { Bh = wvh; Bl = wvl; bn = (bx - 20) * 128; Nout = KVDIM; mode = 2; }

    const hf* Ah = xh; const hf* Al = xl;
    DECLARE_MAINLOOP
    RUN_MAINLOOP

    if (mode == 1) {
        const float scale = 32.f / 65536.f;
#pragma unroll
        for (int j = 0; j < 4; ++j) {
            const int col = bn + wn + j * 16 + fr;
#pragma unroll
            for (int i = 0; i < 4; ++i) {
                const int row0 = bm + wm + i * 16 + fq * 4;
#pragma unroll
                for (int r = 0; r < 4; ++r) {
                    const size_t idx = (size_t)(row0 + r) * Nout + col;
                    float v = acc[i][j][r] * scale;
                    hf h = (hf)v;
                    Oh[idx] = h;
                    Ol[idx] = (hf)(v - (float)h);
                }
            }
        }
    } else {
        const float scale = 1.f / 65536.f;
#pragma unroll
        for (int j = 0; j < 4; ++j) {
            const int col = bn + wn + j * 16 + fr;             // d index
#pragma unroll
            for (int i = 0; i < 4; ++i) {
                const int row0 = bm + wm + i * 16 + fq * 4;    // seq index
                hf4 pk = {(hf)(acc[i][j][0] * scale), (hf)(acc[i][j][1] * scale),
                          (hf)(acc[i][j][2] * scale), (hf)(acc[i][j][3] * scale)};
                *(hf4*)(vT + (size_t)col * MTOT + row0) = pk;
            }
        }
    }
}

// ---------------------------------------------------------------------------
// Output projection (unchanged from R7).
// ---------------------------------------------------------------------------
__global__ __launch_bounds__(256, 2)
void gemm_out(const hf* __restrict__ Ah, const hf* __restrict__ Al,
              const hf* __restrict__ Bh, const hf* __restrict__ Bl,
              const float* __restrict__ bias, float* __restrict__ Cf)
{
    const int tid = threadIdx.x;
    const int lane = tid & 63, wave = tid >> 6;
    const int fr = lane & 15, fq = lane >> 4;
    const int wm = (wave & 1) * 64, wn = (wave >> 1) * 64;
    const int bm = blockIdx.y * 128, bn = blockIdx.x * 128;

    DECLARE_MAINLOOP
    RUN_MAINLOOP

    const float scale = 1.f / 65536.f;
#pragma unroll
    for (int j = 0; j < 4; ++j) {
        const int col = bn + wn + j * 16 + fr;
        const float bv = bias[col];
#pragma unroll
        for (int i = 0; i < 4; ++i) {
            const int row0 = bm + wm + i * 16 + fq * 4;
#pragma unroll
            for (int r = 0; r < 4; ++r)
                Cf[(size_t)(row0 + r) * HID + col] = acc[i][j][r] * scale + bv;
        }
    }
}

// ---------------------------------------------------------------------------
// Attention, S^T orientation, LDS-FREE. The P C-layout -> B-operand transform
// is done in registers with gfx950 v_permlane32/16_swap (VALU, no DS pipe):
//   per q-tile: pack exp results (pkrtz), then
//   swap32(a0,c0) -> swap16 -> B-regs {t0,t2};  (a1,c1) -> {t1,t3}.
// Derivation checked element-wise: B-frag k = 8*fq + j over the 32-kv chunk.
// K register double-buffer with constant indices (R5 lesson). No barriers.
// ---------------------------------------------------------------------------
__global__ __launch_bounds__(256, 2)
void attn_st(const hf* __restrict__ Qhg, const hf* __restrict__ Qlg,
             const hf* __restrict__ Khg, const hf* __restrict__ Klg,
             const hf* __restrict__ Vtg,
             hf* __restrict__ Ohg, hf* __restrict__ Olg)
{
    const int tid  = threadIdx.x;
    const int lane = tid & 63, wave = tid >> 6;
    const int fr = lane & 15, fq = lane >> 4;
    const int hd = blockIdx.y, b = blockIdx.z;
    const int kvh = hd >> 2;
    const int qbase = blockIdx.x * 256 + wave * 64;
    // S_true = S_raw/8192; exp(S_true) = exp2(S_raw * log2(e)/8192)
    const float SS2 = 1.4426950408889634f / 8192.f;

    // persistent Q fragments (B-operand: n=q-row=fr, k=d=fq*8+u+32s)
    hf8 qfh[4][2], qfl[4][2];
#pragma unroll
    for (int nt = 0; nt < 4; ++nt) {
        const size_t rb = (size_t)(b * SEQ + qbase + nt * 16 + fr) * HID + hd * 64;
#pragma unroll
        for (int s = 0; s < 2; ++s) {
            qfh[nt][s] = *(const hf8*)(Qhg + rb + s * 32 + fq * 8);
            qfl[nt][s] = *(const hf8*)(Qlg + rb + s * 32 + fq * 8);
        }
    }

    f32x4 oacc[4][4];                 // O^T tiles [d-tile][q-tile]
#pragma unroll
    for (int i = 0; i < 4; ++i)
#pragma unroll
        for (int j = 0; j < 4; ++j) oacc[i][j] = {0.f, 0.f, 0.f, 0.f};
    float lsum[4] = {0.f, 0.f, 0.f, 0.f};

    const size_t kbase = (size_t)(b * SEQ) * KVDIM + kvh * 64;
    const size_t vbase = (size_t)(kvh * 64) * MTOT + (size_t)(b * SEQ);

    hf8 k0h[2][2], k0l[2][2], k1h[2][2], k1l[2][2];   // [mt][s]

#define LOADK(KH, KL, t0) do { \
    _Pragma("unroll") for (int mt = 0; mt < 2; ++mt) { \
        const size_t kr = kbase + (size_t)((t0) + mt * 16 + fr) * KVDIM; \
        _Pragma("unroll") for (int s = 0; s < 2; ++s) { \
            KH[mt][s] = *(const hf8*)(Khg + kr + s * 32 + fq * 8); \
            KL[mt][s] = *(const hf8*)(Klg + kr + s * 32 + fq * 8); \
        } } } while (0)

#define CHUNK_BODY(KH, KL, t0) do { \
    hf8 vfr[4]; \
    _Pragma("unroll") for (int dt = 0; dt < 4; ++dt) \
        vfr[dt] = *(const hf8*)(Vtg + vbase + (size_t)(dt * 16 + fr) * MTOT \
                                + (t0) + fq * 8); \
    f32x4 sacc[2][4]; \
    _Pragma("unroll") for (int mt = 0; mt < 2; ++mt) \
    _Pragma("unroll") for (int nt = 0; nt < 4; ++nt) sacc[mt][nt] = {0.f,0.f,0.f,0.f}; \
    _Pragma("unroll") for (int mt = 0; mt < 2; ++mt) \
    _Pragma("unroll") for (int nt = 0; nt < 4; ++nt) \
    _Pragma("unroll") for (int s = 0; s < 2; ++s) { \
        sacc[mt][nt] = MFMA16(KH[mt][s], qfh[nt][s], sacc[mt][nt]); \
        sacc[mt][nt] = MFMA16(KH[mt][s], qfl[nt][s], sacc[mt][nt]); \
        sacc[mt][nt] = MFMA16(KL[mt][s], qfh[nt][s], sacc[mt][nt]); \
    } \
    hf8 pb[4]; \
    _Pragma("unroll") for (int nt = 0; nt < 4; ++nt) { \
        float e0 = __builtin_amdgcn_exp2f(sacc[0][nt][0] * SS2); \
        float e1 = __builtin_amdgcn_exp2f(sacc[0][nt][1] * SS2); \
        float e2 = __builtin_amdgcn_exp2f(sacc[0][nt][2] * SS2); \
        float e3 = __builtin_amdgcn_exp2f(sacc[0][nt][3] * SS2); \
        float g0 = __builtin_amdgcn_exp2f(sacc[1][nt][0] * SS2); \
        float g1 = __builtin_amdgcn_exp2f(sacc[1][nt][1] * SS2); \
        float g2 = __builtin_amdgcn_exp2f(sacc[1][nt][2] * SS2); \
        float g3 = __builtin_amdgcn_exp2f(sacc[1][nt][3] * SS2); \
        lsum[nt] += ((e0 + e1) + (e2 + e3)) + ((g0 + g1) + (g2 + g3)); \
        int a0 = pk2(e0, e1), a1 = pk2(e2, e3); \
        int c0 = pk2(g0, g1), c1 = pk2(g2, g3); \
        iv2 u0 = __builtin_amdgcn_permlane32_swap(a0, c0, false, false); \
        iv2 v0 = __builtin_amdgcn_permlane16_swap(u0.x, u0.y, false, false); \
        iv2 u1 = __builtin_amdgcn_permlane32_swap(a1, c1, false, false); \
        iv2 v1 = __builtin_amdgcn_permlane16_swap(u1.x, u1.y, false, false); \
        iv4 bq = {v0.x, v1.x, v0.y, v1.y}; \
        pb[nt] = __builtin_bit_cast(hf8, bq); \
    } \
    _Pragma("unroll") for (int dt = 0; dt < 4; ++dt) \
    _Pragma("unroll") for (int qt = 0; qt < 4; ++qt) \
        oacc[dt][qt] = MFMA16(vfr[dt], pb[qt], oacc[dt][qt]); \
} while (0)

    LOADK(k0h, k0l, 0);
    for (int t0 = 0; t0 < SEQ; t0 += 64) {
        LOADK(k1h, k1l, t0 + 32);          // prefetch odd chunk
        CHUNK_BODY(k0h, k0l, t0);          // compute even chunk
        if (t0 + 64 < SEQ) LOADK(k0h, k0l, t0 + 64);   // prefetch next even
        CHUNK_BODY(k1h, k1l, t0 + 32);     // compute odd chunk
    }
#undef LOADK
#undef CHUNK_BODY

#pragma unroll
    for (int qt = 0; qt < 4; ++qt) {
        lsum[qt] += __shfl_xor(lsum[qt], 16, 64);
        lsum[qt] += __shfl_xor(lsum[qt], 32, 64);
    }

    // epilogue: attn = O/l, store split(256*attn) in A-PANEL layout.
#pragma unroll
    for (int qt = 0; qt < 4; ++qt) {
        const float inv = 256.f / lsum[qt];
        const int pq = ((b * SEQ + qbase) >> 4) + qt;
#pragma unroll
        for (int dt = 0; dt < 4; ++dt) {
            float o0 = oacc[dt][qt][0] * inv, o1 = oacc[dt][qt][1] * inv;
            float o2 = oacc[dt][qt][2] * inv, o3 = oacc[dt][qt][3] * inv;
            hf h0 = (hf)o0, h1 = (hf)o1, h2 = (hf)o2, h3 = (hf)o3;
            hf4 hv = {h0, h1, h2, h3};
            hf4 lv = {(hf)(o0 - (float)h0), (hf)(o1 - (float)h1),
                      (hf)(o2 - (float)h2), (hf)(o3 - (float)h3)};
            const int kb = hd * 2 + (dt >> 1);
            const size_t d = (size_t)pq * 32768 + (size_t)kb * 512
                           + fr * 32 + (dt & 1) * 16 + fq * 4;
            *(hf4*)(Ohg + d) = hv;
            *(hf4*)(Olg + d) = lv;
        }
    }
}

// ---------------------------------------------------------------------------
extern "C" void kernel_launch(void* const* d_in, const int* in_sizes, int n_in,
                              void* d_out, int out_size, void* d_ws, size_t ws_size,
                              hipStream_t stream)
{
    const float* x  = (const float*)d_in[0];
    const float* Wq = (const float*)d_in[1];
    const float* Wk = (const float*)d_in[2];
    const float* Wv = (const float*)d_in[3];
    const float* Wo = (const float*)d_in[4];
    const float* bo = (const float*)d_in[5];
    float* out = (float*)d_out;
    (void)in_sizes; (void)n_in; (void)out_size; (void)ws_size;

    // workspace (halves), 116 MB. xh/xl reused as attn-output panels.
    hf* p = (hf*)d_ws;
    hf* xh  = p; p += (size_t)MTOT * HID;
    hf* xl  = p; p += (size_t)MTOT * HID;
    hf* qh  = p; p += (size_t)MTOT * HID;
    hf* ql  = p; p += (size_t)MTOT * HID;
    hf* kh  = p; p += (size_t)MTOT * KVDIM;
    hf* kl  = p; p += (size_t)MTOT * KVDIM;
    hf* vT  = p; p += (size_t)MTOT * KVDIM;
    hf* wqh = p; p += (size_t)HID * HID;
    hf* wql = p; p += (size_t)HID * HID;
    hf* wkh = p; p += (size_t)KVDIM * HID;
    hf* wkl = p; p += (size_t)KVDIM * HID;
    hf* wvh = p; p += (size_t)KVDIM * HID;
    hf* wvl = p; p += (size_t)KVDIM * HID;
    hf* woh = p; p += (size_t)HID * HID;
    hf* wol = p; p += (size_t)HID * HID;

    split_all<<<18432, 256, 0, stream>>>(x, Wq, Wk, Wv, Wo,
        xh, xl, wqh, wql, wkh, wkl, wvh, wvl, woh, wol);

    gemm_qkv<<<dim3(24, MTOT / 128), 256, 0, stream>>>(
        xh, xl, wqh, wql, wkh, wkl, wvh, wvl, qh, ql, kh, kl, vT);

    attn_st<<<dim3(SEQ / 256, NHEADS, BATCH), 256, 0, stream>>>(
        qh, ql, kh, kl, vT, xh, xl);

    gemm_out<<<dim3(HID / 128, MTOT / 128), 256, 0, stream>>>(
        xh, xl, woh, wol, bo, out);
}